// Round 8
// baseline (364.784 us; speedup 1.0000x reference)
//
#include <hip/hip_runtime.h>

#define BATCH 8
#define CH    64
#define HH    112
#define WW    112
#define HW    (HH * WW)          // 12544
#define NP    (BATCH * HW)       // 100352 pixels
#define TAPS  25
#define MIDC  256
#define PIX   64                 // pixels per block (= 1 wave-width group)
#define CPW   16                 // channels per wave (4 waves * 16 = 64)
#define NBLK  (NP / PIX)         // 1568 blocks
#define NXCD  8
#define CPX   (NBLK / NXCD)      // 196 blocks per XCD == blocks per image
#define WTAP  (CH * TAPS)        // 1600 floats per tap slab
#define WPAD  28                 // padded o-stride in LDS (112B, 16B-aligned)

// ---------------------------------------------------------------------------
// Kernel A: fold conv2 (1x1, 256->25) into conv1 weights.
// R8 layout: weff[tap][c][o] — per-tap slab is 1600 CONTIGUOUS floats so the
// main kernel can stage it into LDS with perfectly coalesced vector loads.
//   weff[((tap*CH)+c)*25 + o] = sum_mid w2[o][mid] * w1[mid][c][tap]
// ---------------------------------------------------------------------------
#define WEFF_N   (CH * TAPS * TAPS)   // 40000
#define WEFF_TOT (WEFF_N + TAPS)      // 40025 (beff appended)
__global__ __launch_bounds__(256) void weff_kernel(
    const float* __restrict__ w1, const float* __restrict__ b1,
    const float* __restrict__ w2, const float* __restrict__ b2,
    float* __restrict__ weff, float* __restrict__ beff) {
  __shared__ float part[3][64];              // chunks 1..3 park partials
  const int lane  = threadIdx.x & 63;
  const int chunk = threadIdx.x >> 6;        // mid in [chunk*64, chunk*64+64)
  const int id    = blockIdx.x * 64 + lane;

  float acc = 0.f;
  if (id < WEFF_N) {
    const int tap = id % TAPS;
    const int t2  = id / TAPS;
    const int o   = t2 % TAPS;
    const int c   = t2 / TAPS;
    const float* w2o = w2 + o * MIDC + chunk * 64;
    const float* w1p = w1 + ((size_t)(chunk * 64) * CH + c) * TAPS + tap;
    float a0 = 0.f, a1 = 0.f;
    #pragma unroll 8
    for (int m = 0; m < 64; m += 2) {
      a0 = fmaf(w1p[(size_t)m       * CH * TAPS], w2o[m],     a0);
      a1 = fmaf(w1p[(size_t)(m + 1) * CH * TAPS], w2o[m + 1], a1);
    }
    acc = a0 + a1;
  } else if (id < WEFF_TOT) {
    const int o = id - WEFF_N;
    const float* w2o = w2 + o * MIDC + chunk * 64;
    const float* b1p = b1 + chunk * 64;
    #pragma unroll 8
    for (int m = 0; m < 64; ++m) acc = fmaf(w2o[m], b1p[m], acc);
  }

  if (chunk) part[chunk - 1][lane] = acc;
  __syncthreads();
  if (chunk == 0 && id < WEFF_TOT) {
    float r = acc + part[0][lane] + part[1][lane] + part[2][lane];
    if (id < WEFF_N) {
      const int tap = id % TAPS;
      const int t2  = id / TAPS;
      const int o   = t2 % TAPS;
      const int c   = t2 / TAPS;
      weff[((size_t)tap * CH + c) * TAPS + o] = r;     // [tap][c][o]
    } else {
      beff[id - WEFF_N] = r + b2[id - WEFF_N];
    }
  }
}

// ---------------------------------------------------------------------------
// Kernel B. R8 change (weights ONLY; x-path/reduce/softmax/phase2 = R6):
// The R6 inner loop consumed 25 scalar-loaded weights per (tap,c). SMEM
// returns out-of-order -> compiler must lgkmcnt(0)-DRAIN before each use:
// ~400 drains/thread, ~40-150cy each vs 50cy FMA per chunk = the 45% stall.
// R8 stages each tap's 6.4KB weight slab in LDS (padded [c][28], uniform-addr
// broadcast ds_read_b128). DS returns IN-order -> fine lgkmcnt(N) pipelining
// under the 800cy FMA block. Staging is T14-split: global->reg issued at
// iteration top (hidden under FMAs), ds_write after the barrier.
// ---------------------------------------------------------------------------
__global__ __launch_bounds__(256, 6) void picanet_main(
    const float* __restrict__ x, const float* __restrict__ weff,
    const float* __restrict__ beff, float* __restrict__ out) {
  __shared__ float wlds[CH * WPAD];           // 7.2 KB weight slab (one tap)
  __shared__ float red[2 * PIX * TAPS];       // 12.8 KB  (total 20 KB)

  const int tid  = threadIdx.x;
  const int lane = tid & 63;
  const int wave = tid >> 6;
  const int c0 = __builtin_amdgcn_readfirstlane(wave * CPW);

  // XCD-aware bijective remap: image b pinned to XCD b (3.2 MB < 4 MB L2).
  const int lb = (blockIdx.x & (NXCD - 1)) * CPX + (blockIdx.x >> 3);
  const int p  = lb * PIX + lane;             // NP % 64 == 0, no tail
  const int b  = p / HW;
  const int hw = p % HW;
  const int h  = hw / WW;
  const int w  = hw % WW;

  const float* xb = x + (size_t)b * CH * HW + (size_t)c0 * HW;

  // ---- stage tap 0 slab ----
  {
    const float* wg = weff;                   // tap 0 slab
    #pragma unroll
    for (int k = 0; k < 7; ++k) {
      int e = tid + k * 256;
      if (e < WTAP) { int c = e / 25, o = e - c * 25; wlds[c * WPAD + o] = wg[e]; }
    }
  }
  __syncthreads();

  // ---- Phase 1: partial logits over this wave's 16 channels ----
  float s[TAPS];
  #pragma unroll
  for (int o = 0; o < TAPS; ++o) s[o] = 0.f;

  #pragma unroll 1
  for (int tap = 0; tap < TAPS; ++tap) {
    // prefetch next tap's slab into regs (consumed after the barrier)
    float pw[7];
    if (tap < TAPS - 1) {
      const float* wg = weff + (size_t)(tap + 1) * WTAP;
      #pragma unroll
      for (int k = 0; k < 7; ++k) {
        int e = tid + k * 256;
        pw[k] = (e < WTAP) ? wg[e] : 0.f;
      }
    }

    int i = tap / 5, j = tap % 5;
    int yy = h + 2 * i - 4;
    int xx = w + 2 * j - 4;
    if (yy >= 0 && yy < HH && xx >= 0 && xx < WW) {
      const float* xp = xb + yy * WW + xx;
      float xv[CPW];
      #pragma unroll
      for (int c = 0; c < CPW; ++c) xv[c] = xp[(size_t)c * HW];
      #pragma unroll
      for (int c = 0; c < CPW; ++c) {
        const float* wp = wlds + (c0 + c) * WPAD;   // uniform -> broadcast ds
        #pragma unroll
        for (int o = 0; o < TAPS; ++o) s[o] = fmaf(xv[c], wp[o], s[o]);
      }
    }

    __syncthreads();                          // all reads of wlds done
    if (tap < TAPS - 1) {
      #pragma unroll
      for (int k = 0; k < 7; ++k) {
        int e = tid + k * 256;
        if (e < WTAP) { int c = e / 25, o = e - c * 25; wlds[c * WPAD + o] = pw[k]; }
      }
    }
    __syncthreads();                          // next slab visible
  }

  // ---- Tree reduce across waves (12.8 KB) ----
  if (wave >= 2) {
    float* dst = red + (wave - 2) * (PIX * TAPS);
    #pragma unroll
    for (int o = 0; o < TAPS; ++o) dst[lane * TAPS + o] = s[o];
  }
  __syncthreads();
  if (wave < 2) {
    const float* srcp = red + wave * (PIX * TAPS);
    #pragma unroll
    for (int o = 0; o < TAPS; ++o) s[o] += srcp[lane * TAPS + o];
  }
  if (wave == 1) {
    float* dst = red + (PIX * TAPS);
    #pragma unroll
    for (int o = 0; o < TAPS; ++o) dst[lane * TAPS + o] = s[o];
  }
  __syncthreads();

  // ---- Softmax: full 64-lane wave 0, one pixel per lane ----
  if (wave == 0) {
    const float* srcp = red + (PIX * TAPS);
    float t[TAPS];
    #pragma unroll
    for (int o = 0; o < TAPS; ++o)
      t[o] = s[o] + srcp[lane * TAPS + o] + beff[o];
    float m = t[0];
    #pragma unroll
    for (int o = 1; o < TAPS; ++o) m = fmaxf(m, t[o]);
    float sum = 0.f;
    #pragma unroll
    for (int o = 0; o < TAPS; ++o) { t[o] = __expf(t[o] - m); sum += t[o]; }
    float inv = 1.f / sum;
    #pragma unroll
    for (int o = 0; o < TAPS; ++o) red[lane * TAPS + o] = t[o] * inv;
  }
  __syncthreads();

  // ---- Phase 2: out[b,c,h,w] = sum_tap sfin[tap] * x[b,c,tap(h,w)] ----
  float acc[CPW];
  #pragma unroll
  for (int c = 0; c < CPW; ++c) acc[c] = 0.f;

  #pragma unroll 1
  for (int tap = 0; tap < TAPS; ++tap) {
    int i = tap / 5, j = tap % 5;
    int yy = h + 2 * i - 4;
    int xx = w + 2 * j - 4;
    float sv = red[lane * TAPS + tap];
    if (yy >= 0 && yy < HH && xx >= 0 && xx < WW) {
      const float* xp = xb + yy * WW + xx;
      #pragma unroll
      for (int c = 0; c < CPW; ++c)
        acc[c] = fmaf(sv, xp[(size_t)c * HW], acc[c]);
    }
  }

  float* ob = out + (size_t)b * CH * HW + (size_t)c0 * HW + hw;
  #pragma unroll
  for (int c = 0; c < CPW; ++c) ob[c * HW] = acc[c];
}

extern "C" void kernel_launch(void* const* d_in, const int* in_sizes, int n_in,
                              void* d_out, int out_size, void* d_ws, size_t ws_size,
                              hipStream_t stream) {
  const float* x  = (const float*)d_in[0];
  const float* w1 = (const float*)d_in[1];
  const float* b1 = (const float*)d_in[2];
  const float* w2 = (const float*)d_in[3];
  const float* b2 = (const float*)d_in[4];
  float* out  = (float*)d_out;
  float* weff = (float*)d_ws;                       // 40000 floats
  float* beff = weff + WEFF_N;                      // 25 floats

  weff_kernel<<<(WEFF_TOT + 63) / 64, 256, 0, stream>>>(
      w1, b1, w2, b2, weff, beff);
  picanet_main<<<NBLK, 256, 0, stream>>>(x, weff, beff, out);
}

// Round 9
// 283.060 us; speedup vs baseline: 1.2887x; 1.2887x over previous
//
#include <hip/hip_runtime.h>

#define BATCH 8
#define CH    64
#define HH    112
#define WW    112
#define HW    (HH * WW)          // 12544
#define NP    (BATCH * HW)       // 100352 pixels
#define TAPS  25
#define MIDC  256
#define PIX   64                 // pixels per block (= 1 wave-width group)
#define CPW   16                 // channels per wave (4 waves * 16 = 64)
#define NBLK  (NP / PIX)         // 1568 blocks
#define NXCD  8
#define CPX   (NBLK / NXCD)      // 196 blocks per XCD == blocks per image
#define WPAD  28                 // padded o-stride (112 B, 16B-aligned rows)
#define WSLAB (CH * WPAD)        // 1792 floats per tap slab (7168 B)

// ---------------------------------------------------------------------------
// Kernel A: fold conv2 (1x1, 256->25) into conv1 weights.
// R9 layout: weff[tap][c][28] PRE-PADDED IN GLOBAL, so the main kernel's
// LDS staging is a pure linear float4 copy (no re-layout, no divides) and
// LDS rows are 16B-aligned for ds_read_b128 broadcasts. Pad never read.
//   weff[((tap*CH)+c)*28 + o] = sum_mid w2[o][mid] * w1[mid][c][tap]
// ---------------------------------------------------------------------------
#define WEFF_N   (CH * TAPS * TAPS)   // 40000 logical outputs
#define WEFF_TOT (WEFF_N + TAPS)      // + beff
#define WEFF_PAD (TAPS * WSLAB)       // 44800 padded floats
__global__ __launch_bounds__(256) void weff_kernel(
    const float* __restrict__ w1, const float* __restrict__ b1,
    const float* __restrict__ w2, const float* __restrict__ b2,
    float* __restrict__ weff, float* __restrict__ beff) {
  __shared__ float part[3][64];              // chunks 1..3 park partials
  const int lane  = threadIdx.x & 63;
  const int chunk = threadIdx.x >> 6;        // mid in [chunk*64, chunk*64+64)
  const int id    = blockIdx.x * 64 + lane;

  float acc = 0.f;
  if (id < WEFF_N) {
    const int tap = id % TAPS;
    const int t2  = id / TAPS;
    const int o   = t2 % TAPS;
    const int c   = t2 / TAPS;
    const float* w2o = w2 + o * MIDC + chunk * 64;
    const float* w1p = w1 + ((size_t)(chunk * 64) * CH + c) * TAPS + tap;
    float a0 = 0.f, a1 = 0.f;
    #pragma unroll 8
    for (int m = 0; m < 64; m += 2) {
      a0 = fmaf(w1p[(size_t)m       * CH * TAPS], w2o[m],     a0);
      a1 = fmaf(w1p[(size_t)(m + 1) * CH * TAPS], w2o[m + 1], a1);
    }
    acc = a0 + a1;
  } else if (id < WEFF_TOT) {
    const int o = id - WEFF_N;
    const float* w2o = w2 + o * MIDC + chunk * 64;
    const float* b1p = b1 + chunk * 64;
    #pragma unroll 8
    for (int m = 0; m < 64; ++m) acc = fmaf(w2o[m], b1p[m], acc);
  }

  if (chunk) part[chunk - 1][lane] = acc;
  __syncthreads();
  if (chunk == 0 && id < WEFF_TOT) {
    float r = acc + part[0][lane] + part[1][lane] + part[2][lane];
    if (id < WEFF_N) {
      const int tap = id % TAPS;
      const int t2  = id / TAPS;
      const int o   = t2 % TAPS;
      const int c   = t2 / TAPS;
      weff[((size_t)tap * CH + c) * WPAD + o] = r;     // padded [tap][c][28]
    } else {
      beff[id - WEFF_N] = r + b2[id - WEFF_N];
    }
  }
}

// ---------------------------------------------------------------------------
// Kernel B. R9 change (weight path ONLY; x-path/reduce/softmax/phase2 = R6):
// R6 issued ~1 scalar weight dword per FMA; SMEM is out-of-order so every
// batch needs an lgkmcnt(0) DRAIN to L2 (~200cy) -> the pinned 55% VALUBusy.
// R9 stages each tap's 7KB padded slab in LDS via single-barrier double
// buffering: {vmcnt-wait -> ds_write slab[t&1] -> issue loads(t+1) ->
// barrier -> FMA reads slab[t&1] via wave-uniform ds_read_b128 broadcasts}.
// DS returns in-order -> fine lgkmcnt pipelining; only 8 VGPRs (2 float4s)
// live across the FMA block (R8's spill killer removed). red aliases slab1
// (disjoint from slab0 which tap 24 reads) -> 19.97 KB total LDS.
// ---------------------------------------------------------------------------
__global__ __launch_bounds__(256, 6) void picanet_main(
    const float* __restrict__ x, const float* __restrict__ weff,
    const float* __restrict__ beff, float* __restrict__ out) {
  __shared__ float pool[WSLAB + 2 * PIX * TAPS];  // 1792 + 3200 = 19968 B
  float* red = pool + WSLAB;                      // aliases slab1 region

  const int tid  = threadIdx.x;
  const int lane = tid & 63;
  const int wave = tid >> 6;
  const int c0 = __builtin_amdgcn_readfirstlane(wave * CPW);

  // XCD-aware bijective remap: image b pinned to XCD b (3.2 MB < 4 MB L2).
  const int lb = (blockIdx.x & (NXCD - 1)) * CPX + (blockIdx.x >> 3);
  const int p  = lb * PIX + lane;             // NP % 64 == 0, no tail
  const int b  = p / HW;
  const int hw = p % HW;
  const int h  = hw / WW;
  const int w  = hw % WW;

  const float* xb = x + (size_t)b * CH * HW + (size_t)c0 * HW;

  // ---- Phase 1: partial logits, weights LDS-staged per tap ----
  float s[TAPS];
  #pragma unroll
  for (int o = 0; o < TAPS; ++o) s[o] = 0.f;

  // prologue: issue tap 0 slab loads (448 float4s: k=0 all, k=1 tid<192)
  float4 nv0, nv1;
  {
    const float4* wg4 = (const float4*)weff;
    nv0 = wg4[tid];
    nv1 = (tid < 192) ? wg4[256 + tid] : make_float4(0.f, 0.f, 0.f, 0.f);
  }

  #pragma unroll 1
  for (int tap = 0; tap < TAPS; ++tap) {
    const int sb = (tap & 1) * WSLAB;         // this tap's slab base

    // commit staged data (compiler inserts the vmcnt wait on nv0/nv1)
    {
      float4* wl4 = (float4*)(pool + sb);
      wl4[tid] = nv0;
      if (tid < 192) wl4[256 + tid] = nv1;
    }
    // issue next tap's loads (latency hides under barrier + FMA block)
    if (tap < TAPS - 1) {
      const float4* wg4 = (const float4*)(weff + (size_t)(tap + 1) * WSLAB);
      nv0 = wg4[tid];
      nv1 = (tid < 192) ? wg4[256 + tid] : make_float4(0.f, 0.f, 0.f, 0.f);
    }
    __syncthreads();                          // slab[t&1] visible to all

    int i = tap / 5, j = tap % 5;
    int yy = h + 2 * i - 4;
    int xx = w + 2 * j - 4;
    if (yy >= 0 && yy < HH && xx >= 0 && xx < WW) {
      const float* xp = xb + yy * WW + xx;
      float xv[CPW];
      #pragma unroll
      for (int c = 0; c < CPW; ++c) xv[c] = xp[(size_t)c * HW];
      #pragma unroll
      for (int c = 0; c < CPW; ++c) {
        // wave-uniform address -> broadcast ds_read_b128, in-order lgkm
        const float* wp = pool + sb + (c0 + c) * WPAD;
        #pragma unroll
        for (int o = 0; o < TAPS; ++o) s[o] = fmaf(xv[c], wp[o], s[o]);
      }
    }
  }
  // NOTE: no barrier needed here — red aliases slab1; tap 24 reads slab0
  // (disjoint), and all waves passed barrier(24) already.

  // ---- Tree reduce across waves (12.8 KB in red) ----
  if (wave >= 2) {
    float* dst = red + (wave - 2) * (PIX * TAPS);
    #pragma unroll
    for (int o = 0; o < TAPS; ++o) dst[lane * TAPS + o] = s[o];
  }
  __syncthreads();
  if (wave < 2) {
    const float* srcp = red + wave * (PIX * TAPS);
    #pragma unroll
    for (int o = 0; o < TAPS; ++o) s[o] += srcp[lane * TAPS + o];
  }
  if (wave == 1) {
    float* dst = red + (PIX * TAPS);
    #pragma unroll
    for (int o = 0; o < TAPS; ++o) dst[lane * TAPS + o] = s[o];
  }
  __syncthreads();

  // ---- Softmax: full 64-lane wave 0, one pixel per lane ----
  if (wave == 0) {
    const float* srcp = red + (PIX * TAPS);
    float t[TAPS];
    #pragma unroll
    for (int o = 0; o < TAPS; ++o)
      t[o] = s[o] + srcp[lane * TAPS + o] + beff[o];
    float m = t[0];
    #pragma unroll
    for (int o = 1; o < TAPS; ++o) m = fmaxf(m, t[o]);
    float sum = 0.f;
    #pragma unroll
    for (int o = 0; o < TAPS; ++o) { t[o] = __expf(t[o] - m); sum += t[o]; }
    float inv = 1.f / sum;
    #pragma unroll
    for (int o = 0; o < TAPS; ++o) red[lane * TAPS + o] = t[o] * inv;
  }
  __syncthreads();

  // ---- Phase 2: out[b,c,h,w] = sum_tap sfin[tap] * x[b,c,tap(h,w)] ----
  float acc[CPW];
  #pragma unroll
  for (int c = 0; c < CPW; ++c) acc[c] = 0.f;

  #pragma unroll 1
  for (int tap = 0; tap < TAPS; ++tap) {
    int i = tap / 5, j = tap % 5;
    int yy = h + 2 * i - 4;
    int xx = w + 2 * j - 4;
    float sv = red[lane * TAPS + tap];
    if (yy >= 0 && yy < HH && xx >= 0 && xx < WW) {
      const float* xp = xb + yy * WW + xx;
      #pragma unroll
      for (int c = 0; c < CPW; ++c)
        acc[c] = fmaf(sv, xp[(size_t)c * HW], acc[c]);
    }
  }

  float* ob = out + (size_t)b * CH * HW + (size_t)c0 * HW + hw;
  #pragma unroll
  for (int c = 0; c < CPW; ++c) ob[c * HW] = acc[c];
}

extern "C" void kernel_launch(void* const* d_in, const int* in_sizes, int n_in,
                              void* d_out, int out_size, void* d_ws, size_t ws_size,
                              hipStream_t stream) {
  const float* x  = (const float*)d_in[0];
  const float* w1 = (const float*)d_in[1];
  const float* b1 = (const float*)d_in[2];
  const float* w2 = (const float*)d_in[3];
  const float* b2 = (const float*)d_in[4];
  float* out  = (float*)d_out;
  float* weff = (float*)d_ws;                       // 44800 padded floats
  float* beff = weff + WEFF_PAD;                    // 25 floats

  weff_kernel<<<(WEFF_TOT + 63) / 64, 256, 0, stream>>>(
      w1, b1, w2, b2, weff, beff);
  picanet_main<<<NBLK, 256, 0, stream>>>(x, weff, beff, out);
}